// Round 4
// baseline (17335.831 us; speedup 1.0000x reference)
//
#include <hip/hip_runtime.h>

typedef unsigned short u16;   // bf16 bits (workspace intermediates only)

#define B_   32
#define N_   1024
#define E_   16384
#define ET_  17408            // E_ + N_ self-loops
#define IN_DIM 768
#define HID  512
#define OUT_ 400
#define PAIR_ 800
#define FEAT_ELEMS 13107200   // B_*N_*OUT_
#define MAXD 128

__device__ __forceinline__ float u2f(u16 u) {
    union { unsigned int i; float f; } v; v.i = ((unsigned int)u) << 16; return v.f;
}
__device__ __forceinline__ u16 f2u(float f) {
    union { float f; unsigned int i; } v; v.f = f;
    unsigned int r = v.i + 0x7FFF + ((v.i >> 16) & 1);   // round-nearest-even
    return (u16)(r >> 16);
}

__device__ __forceinline__ float gelu_f(float x) {
    const float c = 0.7978845608028654f;          // sqrt(2/pi)
    float u = c * (x + 0.044715f * x * x * x);
    float t = 2.0f / (1.0f + __expf(-2.0f * u)) - 1.0f;   // tanh(u), overflow-safe
    return 0.5f * x * (1.0f + t);
}

// ---------------------------------------------------------------------------
// Tiled GEMM: C[M,N] = act(A @ W + bias). W, bias f32 (model inputs).
// ASRC: 0 = f32 A [M,K]; 1 = bf16 ws A [M,K]; 2 = row e gathered as
// concat(feat[src0[e]], feat[dst0[e]]) from f32 feat. C written bf16 (ws).
// M % 64 == 0, K % 16 == 0, N % 4 == 0. N guarded.
// ---------------------------------------------------------------------------
template<int ASRC, bool DO_GELU, bool HAS_BIAS>
__global__ __launch_bounds__(256)
void gemm_k(const float* __restrict__ Af, const u16* __restrict__ Ab,
            const float* __restrict__ W, const float* __restrict__ bias,
            u16* __restrict__ C, int M, int N, int K,
            const float* __restrict__ featb, const int* __restrict__ src0,
            const int* __restrict__ dst0)
{
    __shared__ float As[64][17];    // +1 pad: conflict-free reads
    __shared__ float Bs[16][68];    // +4 pad: breaks 16-way store conflict
    const int bm = blockIdx.y * 64;
    const int bn = blockIdx.x * 64;
    const int tid = threadIdx.x;
    const int tx = tid & 15, ty = tid >> 4;
    const int ar = tid >> 2, aq = (tid & 3) << 2;   // A loader: row, k-quad
    const int wr = tid >> 4, wq = (tid & 15) << 2;  // W loader: k-row, n-quad
    float acc[4][4] = {};

    for (int k0 = 0; k0 < K; k0 += 16) {
        if (ASRC == 0) {
            float4 av = *(const float4*)(Af + (size_t)(bm + ar) * K + (k0 + aq));
            As[ar][aq + 0] = av.x; As[ar][aq + 1] = av.y;
            As[ar][aq + 2] = av.z; As[ar][aq + 3] = av.w;
        } else if (ASRC == 1) {
            ushort4 av = *(const ushort4*)(Ab + (size_t)(bm + ar) * K + (k0 + aq));
            As[ar][aq + 0] = u2f(av.x); As[ar][aq + 1] = u2f(av.y);
            As[ar][aq + 2] = u2f(av.z); As[ar][aq + 3] = u2f(av.w);
        } else {
            int e = bm + ar;
            int kk = k0 + aq;
            int node, kc;
            if (kk < OUT_) { node = src0[e]; kc = kk; }
            else           { node = dst0[e]; kc = kk - OUT_; }
            float4 av = *(const float4*)(featb + (size_t)node * OUT_ + kc);
            As[ar][aq + 0] = av.x; As[ar][aq + 1] = av.y;
            As[ar][aq + 2] = av.z; As[ar][aq + 3] = av.w;
        }

        {
            int wn = bn + wq;
            const float* wp = W + (size_t)(k0 + wr) * N + wn;
            if (wn + 3 < N) {
                float4 wv = *(const float4*)wp;
                Bs[wr][wq + 0] = wv.x; Bs[wr][wq + 1] = wv.y;
                Bs[wr][wq + 2] = wv.z; Bs[wr][wq + 3] = wv.w;
            } else {
                Bs[wr][wq + 0] = (wn + 0 < N) ? wp[0] : 0.f;
                Bs[wr][wq + 1] = (wn + 1 < N) ? wp[1] : 0.f;
                Bs[wr][wq + 2] = (wn + 2 < N) ? wp[2] : 0.f;
                Bs[wr][wq + 3] = (wn + 3 < N) ? wp[3] : 0.f;
            }
        }
        __syncthreads();
#pragma unroll
        for (int kk = 0; kk < 16; ++kk) {
            float a0 = As[ty * 4 + 0][kk], a1 = As[ty * 4 + 1][kk];
            float a2 = As[ty * 4 + 2][kk], a3 = As[ty * 4 + 3][kk];
            float b0 = Bs[kk][tx * 4 + 0], b1 = Bs[kk][tx * 4 + 1];
            float b2 = Bs[kk][tx * 4 + 2], b3 = Bs[kk][tx * 4 + 3];
            acc[0][0] += a0 * b0; acc[0][1] += a0 * b1; acc[0][2] += a0 * b2; acc[0][3] += a0 * b3;
            acc[1][0] += a1 * b0; acc[1][1] += a1 * b1; acc[1][2] += a1 * b2; acc[1][3] += a1 * b3;
            acc[2][0] += a2 * b0; acc[2][1] += a2 * b1; acc[2][2] += a2 * b2; acc[2][3] += a2 * b3;
            acc[3][0] += a3 * b0; acc[3][1] += a3 * b1; acc[3][2] += a3 * b2; acc[3][3] += a3 * b3;
        }
        __syncthreads();
    }
#pragma unroll
    for (int i = 0; i < 4; ++i) {
        int row = bm + ty * 4 + i;
        int col0 = bn + tx * 4;
        float v[4];
#pragma unroll
        for (int j = 0; j < 4; ++j) {
            v[j] = acc[i][j];
            if (HAS_BIAS && col0 + j < N) v[j] += bias[col0 + j];
            if (DO_GELU) v[j] = gelu_f(v[j]);
        }
        if (col0 + 3 < N) {
            ushort4 sv;
            sv.x = f2u(v[0]); sv.y = f2u(v[1]); sv.z = f2u(v[2]); sv.w = f2u(v[3]);
            *(ushort4*)(C + (size_t)row * N + col0) = sv;
        } else {
#pragma unroll
            for (int j = 0; j < 4; ++j)
                if (col0 + j < N) C[(size_t)row * N + col0 + j] = f2u(v[j]);
        }
    }
}

// ---------------------------------------------------------------------------
// Attention scores: a_s[n,h] = sum_f wh[n,h*200+f]*att_src[h*200+f]; same a_d.
// One wave per node (4 waves / block).
// ---------------------------------------------------------------------------
__global__ __launch_bounds__(256)
void scores_k(const u16* __restrict__ wh, const float* __restrict__ att_s,
              const float* __restrict__ att_d, float* __restrict__ a_s,
              float* __restrict__ a_d)
{
    int n = blockIdx.x * 4 + (threadIdx.x >> 6);
    int lane = threadIdx.x & 63;
    const u16* row = wh + (size_t)n * OUT_;
    float as0 = 0, as1 = 0, ad0 = 0, ad1 = 0;
    for (int f = lane; f < OUT_; f += 64) {
        float v = u2f(row[f]);
        float s = att_s[f];
        float d = att_d[f];
        if (f < 200) { as0 += v * s; ad0 += v * d; }
        else         { as1 += v * s; ad1 += v * d; }
    }
    for (int off = 32; off; off >>= 1) {
        as0 += __shfl_xor(as0, off); as1 += __shfl_xor(as1, off);
        ad0 += __shfl_xor(ad0, off); ad1 += __shfl_xor(ad1, off);
    }
    if (lane == 0) {
        a_s[(size_t)n * 2 + 0] = as0; a_s[(size_t)n * 2 + 1] = as1;
        a_d[(size_t)n * 2 + 0] = ad0; a_d[(size_t)n * 2 + 1] = ad1;
    }
}

// ---------------------------------------------------------------------------
// CSR build (edges shared across batches; incl. self-loops)
// ---------------------------------------------------------------------------
__global__ void csr_count_k(const int* __restrict__ edges, int* __restrict__ deg)
{
    int et = blockIdx.x * blockDim.x + threadIdx.x;
    if (et >= ET_) return;
    int dst = (et < E_) ? edges[E_ + et] : (et - E_);
    atomicAdd(&deg[dst], 1);
}

__global__ __launch_bounds__(1024)
void csr_scan_k(const int* __restrict__ deg, int* __restrict__ row_ptr,
                int* __restrict__ cnt)
{
    __shared__ int s[1024];
    int t = threadIdx.x;
    int d = deg[t];
    s[t] = d;
    __syncthreads();
    for (int off = 1; off < 1024; off <<= 1) {
        int v = (t >= off) ? s[t - off] : 0;
        __syncthreads();
        s[t] += v;
        __syncthreads();
    }
    row_ptr[t] = s[t] - d;   // exclusive
    cnt[t] = s[t] - d;
    if (t == 1023) row_ptr[1024] = s[t];
}

__global__ void csr_fill_k(const int* __restrict__ edges, int* __restrict__ cnt,
                           int* __restrict__ col_src)
{
    int et = blockIdx.x * blockDim.x + threadIdx.x;
    if (et >= ET_) return;
    int src, dst;
    if (et < E_) { src = edges[et]; dst = edges[E_ + et]; }
    else         { src = et - E_;  dst = src; }
    int pos = atomicAdd(&cnt[dst], 1);
    col_src[pos] = src;
}

// ---------------------------------------------------------------------------
// Fused GAT softmax + aggregation + residual. One block per (b, node).
// feat_out = enc + segsum(coef * wh[src]) + gat_b  -> f32 straight to d_out
// ---------------------------------------------------------------------------
__global__ __launch_bounds__(256)
void gat_k(const u16* __restrict__ enc, const u16* __restrict__ wh,
           const float* __restrict__ a_s, const float* __restrict__ a_d,
           const int* __restrict__ row_ptr, const int* __restrict__ col_src,
           const float* __restrict__ gat_b, float* __restrict__ feat_out)
{
    int gn = blockIdx.x;                  // b*1024 + n
    int b = gn >> 10, n = gn & 1023;
    int tid = threadIdx.x;
    __shared__ float s_ee[2][MAXD];
    __shared__ int   s_src[MAXD];
    __shared__ float s_misc[6];           // m0,m1,invz0,invz1,ad0,ad1
    int start = row_ptr[n];
    int deg = row_ptr[n + 1] - start;

    if (tid < 64) {
        int lane = tid;
        float ad0 = a_d[(size_t)gn * 2 + 0];
        float ad1 = a_d[(size_t)gn * 2 + 1];
        float m0 = -1e30f, m1 = -1e30f;
        for (int j = lane; j < deg; j += 64) {
            int gs = (b << 10) + col_src[start + j];
            float e0 = a_s[(size_t)gs * 2 + 0] + ad0; e0 = (e0 > 0.f) ? e0 : 0.2f * e0;
            float e1 = a_s[(size_t)gs * 2 + 1] + ad1; e1 = (e1 > 0.f) ? e1 : 0.2f * e1;
            if (j < MAXD) { s_ee[0][j] = e0; s_ee[1][j] = e1; s_src[j] = gs; }
            m0 = fmaxf(m0, e0); m1 = fmaxf(m1, e1);
        }
        for (int off = 32; off; off >>= 1) {
            m0 = fmaxf(m0, __shfl_xor(m0, off));
            m1 = fmaxf(m1, __shfl_xor(m1, off));
        }
        float z0 = 0.f, z1 = 0.f;
        for (int j = lane; j < deg; j += 64) {
            float e0, e1;
            if (j < MAXD) { e0 = s_ee[0][j]; e1 = s_ee[1][j]; }
            else {
                int gs = (b << 10) + col_src[start + j];
                e0 = a_s[(size_t)gs * 2 + 0] + ad0; e0 = (e0 > 0.f) ? e0 : 0.2f * e0;
                e1 = a_s[(size_t)gs * 2 + 1] + ad1; e1 = (e1 > 0.f) ? e1 : 0.2f * e1;
            }
            float t0 = __expf(e0 - m0), t1 = __expf(e1 - m1);
            if (j < MAXD) { s_ee[0][j] = t0; s_ee[1][j] = t1; }
            z0 += t0; z1 += t1;
        }
        for (int off = 32; off; off >>= 1) {
            z0 += __shfl_xor(z0, off);
            z1 += __shfl_xor(z1, off);
        }
        if (lane == 0) {
            s_misc[0] = m0; s_misc[1] = m1;
            s_misc[2] = (z0 > 0.f) ? 1.f / z0 : 0.f;
            s_misc[3] = (z1 > 0.f) ? 1.f / z1 : 0.f;
            s_misc[4] = ad0; s_misc[5] = ad1;
        }
    }
    __syncthreads();
    float m0 = s_misc[0], m1 = s_misc[1];
    float iz0 = s_misc[2], iz1 = s_misc[3];
    float ad0 = s_misc[4], ad1 = s_misc[5];
    for (int c = tid; c < OUT_; c += 256) {
        int h = (c >= 200);
        float acc = 0.f;
        for (int j = 0; j < deg; ++j) {
            float w; int gs;
            if (j < MAXD) { w = s_ee[h][j]; gs = s_src[j]; }
            else {
                gs = (b << 10) + col_src[start + j];
                float e = a_s[(size_t)gs * 2 + h] + (h ? ad1 : ad0);
                e = (e > 0.f) ? e : 0.2f * e;
                w = __expf(e - (h ? m1 : m0));
            }
            acc += w * u2f(wh[(size_t)gs * OUT_ + c]);
        }
        acc *= (h ? iz1 : iz0);
        float v = u2f(enc[(size_t)gn * OUT_ + c]) + acc + gat_b[c];
        feat_out[(size_t)gn * OUT_ + c] = v;
    }
}

// ---------------------------------------------------------------------------
// Final tiny GEMM: pred[e,0:3] = p2[e,:] @ w3[400,3] + b3. One wave per edge.
// ---------------------------------------------------------------------------
__global__ __launch_bounds__(64)
void head3_k(const u16* __restrict__ p2, const float* __restrict__ w3,
             const float* __restrict__ b3, float* __restrict__ out, int row_base)
{
    int e = blockIdx.x;
    int lane = threadIdx.x;
    const u16* row = p2 + (size_t)e * OUT_;
    float s0 = 0, s1 = 0, s2 = 0;
    for (int k = lane; k < OUT_; k += 64) {
        float v = u2f(row[k]);
        s0 += v * w3[k * 3 + 0];
        s1 += v * w3[k * 3 + 1];
        s2 += v * w3[k * 3 + 2];
    }
    for (int off = 32; off; off >>= 1) {
        s0 += __shfl_xor(s0, off);
        s1 += __shfl_xor(s1, off);
        s2 += __shfl_xor(s2, off);
    }
    if (lane == 0) {
        size_t o = (size_t)FEAT_ELEMS + (size_t)(row_base + e) * 3;
        out[o + 0] = s0 + b3[0];
        out[o + 1] = s1 + b3[1];
        out[o + 2] = s2 + b3[2];
    }
}

extern "C" void kernel_launch(void* const* d_in, const int* in_sizes, int n_in,
                              void* d_out, int out_size, void* d_ws, size_t ws_size,
                              hipStream_t stream)
{
    const float* patch  = (const float*)d_in[0];   // f32 inputs per reference
    const int*   edges  = (const int*)d_in[1];
    const float* enc_w1 = (const float*)d_in[2];
    const float* enc_b1 = (const float*)d_in[3];
    const float* enc_w2 = (const float*)d_in[4];
    const float* enc_b2 = (const float*)d_in[5];
    const float* gat_w  = (const float*)d_in[6];
    const float* att_s  = (const float*)d_in[7];
    const float* att_d  = (const float*)d_in[8];
    const float* gat_b  = (const float*)d_in[9];
    const float* h_w1   = (const float*)d_in[10];
    const float* h_b1   = (const float*)d_in[11];
    const float* h_w2   = (const float*)d_in[12];
    const float* h_b2   = (const float*)d_in[13];
    const float* h_w3   = (const float*)d_in[14];
    const float* h_b3   = (const float*)d_in[15];
    float* out = (float*)d_out;                     // f32 output (ref dtype)

    // workspace — peak 60.4 MB. Region 0 (33.5 MB): enc1 -> whb -> p2.
    // Region 1 (26.2 MB): encb -> p1. Tail: a_s/a_d + CSR tables.
    char* ws = (char*)d_ws;
    u16* enc1 = (u16*)ws;                     // [32768,512] bf16
    u16* whb  = (u16*)ws;                     // [32768,400] bf16 (after enc1 dead)
    u16* p2   = (u16*)ws;                     // [16384,400] bf16 (after whb dead)
    u16* encb = (u16*)(ws + 33554432);        // [32768,400] bf16
    u16* p1   = encb;                         // [16384,800] bf16 (after encb dead)
    float* a_s = (float*)(ws + 59768832);     // 65,536 f32
    float* a_d = (float*)(ws + 60030976);     // 65,536 f32
    int* deg     = (int*)(ws + 60293120);     // 1024
    int* row_ptr = deg + 1024;                // 1025 (padded to 1032)
    int* cnt     = row_ptr + 1032;            // 1024
    int* col_src = cnt + 1024;                // 17,408   (end = 60,375,072 B)

    const int* src0 = edges;
    const int* dst0 = edges + E_;

    // CSR by dst (batch-independent)
    hipMemsetAsync(deg, 0, 1024 * sizeof(int), stream);
    csr_count_k<<<(ET_ + 255) / 256, 256, 0, stream>>>(edges, deg);
    csr_scan_k<<<1, 1024, 0, stream>>>(deg, row_ptr, cnt);
    csr_fill_k<<<(ET_ + 255) / 256, 256, 0, stream>>>(edges, cnt, col_src);

    // patch encoder: enc1 = gelu(patch @ w1 + b1); enc = enc1 @ w2 + b2
    gemm_k<0, true, true><<<dim3(HID / 64, (B_ * N_) / 64), 256, 0, stream>>>(
        patch, nullptr, enc_w1, enc_b1, enc1, B_ * N_, HID, IN_DIM,
        nullptr, nullptr, nullptr);
    gemm_k<1, false, true><<<dim3((OUT_ + 63) / 64, (B_ * N_) / 64), 256, 0, stream>>>(
        nullptr, enc1, enc_w2, enc_b2, encb, B_ * N_, OUT_, HID,
        nullptr, nullptr, nullptr);

    // GAT linear: wh = enc @ gat_w   (whb overlays dead enc1)
    gemm_k<1, false, false><<<dim3((OUT_ + 63) / 64, (B_ * N_) / 64), 256, 0, stream>>>(
        nullptr, encb, gat_w, nullptr, whb, B_ * N_, OUT_, OUT_,
        nullptr, nullptr, nullptr);

    scores_k<<<(B_ * N_) / 4, 256, 0, stream>>>(whb, att_s, att_d, a_s, a_d);
    gat_k<<<B_ * N_, 256, 0, stream>>>(encb, whb, a_s, a_d, row_ptr, col_src,
                                       gat_b, out);

    // predict head, per batch (pair-gather from f32 feat in d_out)
    for (int b = 0; b < B_; ++b) {
        const float* featb = out + (size_t)b * N_ * OUT_;
        gemm_k<2, true, true><<<dim3((PAIR_ + 63) / 64, E_ / 64), 256, 0, stream>>>(
            nullptr, nullptr, h_w1, h_b1, p1, E_, PAIR_, PAIR_,
            featb, src0, dst0);
        gemm_k<1, true, true><<<dim3((OUT_ + 63) / 64, E_ / 64), 256, 0, stream>>>(
            nullptr, p1, h_w2, h_b2, p2, E_, OUT_, PAIR_,
            nullptr, nullptr, nullptr);
        head3_k<<<E_, 64, 0, stream>>>(p2, h_w3, h_b3, out, b * E_);
    }
}

// Round 5
// 6302.919 us; speedup vs baseline: 2.7504x; 2.7504x over previous
//
#include <hip/hip_runtime.h>
#include <hip/hip_bf16.h>

typedef unsigned short u16;   // bf16 bits
typedef __attribute__((ext_vector_type(8))) short bf16x8;   // MFMA A/B frag (4 VGPRs)
typedef __attribute__((ext_vector_type(4))) float f32x4;    // MFMA C/D frag

#define B_   32
#define N_   1024
#define E_   16384
#define ET_  17408            // E_ + N_ self-loops
#define IN_DIM 768
#define HID  512
#define OUT_ 400
#define PAIR_ 800
#define FEAT_ELEMS 13107200   // B_*N_*OUT_
#define MAXD 128

__device__ __forceinline__ float u2f(u16 u) {
    union { unsigned int i; float f; } v; v.i = ((unsigned int)u) << 16; return v.f;
}
__device__ __forceinline__ u16 f2u(float f) {
    __hip_bfloat16 h = __float2bfloat16(f);   // RNE, HW cvt on gfx950
    return *(u16*)&h;
}
__device__ __forceinline__ unsigned int pack2(float a, float b) {
    return (unsigned int)f2u(a) | ((unsigned int)f2u(b) << 16);
}

__device__ __forceinline__ float gelu_f(float x) {
    const float c = 0.7978845608028654f;          // sqrt(2/pi)
    float u = c * (x + 0.044715f * x * x * x);
    float t = 2.0f / (1.0f + __expf(-2.0f * u)) - 1.0f;   // tanh(u), overflow-safe
    return 0.5f * x * (1.0f + t);
}

// ---------------------------------------------------------------------------
// Weight transpose + bf16 convert: Wt[n][k] = bf16(W[k][n]). Tiny, once/launch.
// ---------------------------------------------------------------------------
__global__ void wt_k(const float* __restrict__ W, u16* __restrict__ Wt,
                     int K, int N)
{
    int i = blockIdx.x * 256 + threadIdx.x;
    if (i >= N * K) return;
    int n = i / K, k = i - n * K;
    Wt[i] = f2u(W[(size_t)k * N + n]);
}

// ---------------------------------------------------------------------------
// MFMA GEMM: C[M,N] = act(A[M,K] @ W[K,N] + bias), f32 accumulate.
// Tile 128x128, BK=64; 4 waves, each 64x64 via 4x4 grid of 16x16x32 MFMAs.
// Wt is pre-transposed bf16 [N][K]. ASRC: 0 = f32 A; 1 = bf16 A;
// 2 = row e gathered as concat(feat[src0[e]], feat[dst0[e]]) from f32 feat.
// M % 128 == 0; K % 8 == 0; N guarded. LDS pitch 72 elems (144 B): quarter-
// wave b128 reads land uniform 2-way on banks (free per m136).
// ---------------------------------------------------------------------------
template<int ASRC, bool DO_GELU, bool HAS_BIAS, bool OUT_F32>
__global__ __launch_bounds__(256)
void mfma_gemm_k(const float* __restrict__ Af, const u16* __restrict__ Ab,
                 const u16* __restrict__ Wt, const float* __restrict__ bias,
                 u16* __restrict__ Cb, float* __restrict__ Cf,
                 int M, int N, int K,
                 const float* __restrict__ featb, const int* __restrict__ src0,
                 const int* __restrict__ dst0)
{
    __shared__ __align__(16) u16 As[128 * 72];
    __shared__ __align__(16) u16 Bs[128 * 72];
    const int tid  = threadIdx.x;
    const int bm   = blockIdx.y * 128;
    const int bn   = blockIdx.x * 128;
    const int row  = tid >> 1;        // 0..127 (staging row)
    const int half = tid & 1;         // 32-elem k-half (staging)
    const int wave = tid >> 6;
    const int lane = tid & 63;
    const int wm   = (wave >> 1) * 64;
    const int wn   = (wave & 1) * 64;
    const int lm   = lane & 15;       // m (A) / n (B,C) within 16-tile
    const int lq   = lane >> 4;       // quad

    int nodeS = 0, nodeD = 0;
    if (ASRC == 2) { int e = bm + row; nodeS = src0[e]; nodeD = dst0[e]; }

    f32x4 acc[4][4] = {};

    for (int k0 = 0; k0 < K; k0 += 64) {
        // ---- stage A: [128][64] bf16, this thread: row, k-half (32 elems)
        #pragma unroll
        for (int c = 0; c < 4; ++c) {
            int kk = k0 + half * 32 + c * 8;
            uint4 wv;
            if (ASRC == 1) {
                wv = (kk < K) ? *(const uint4*)(Ab + (size_t)(bm + row) * K + kk)
                              : make_uint4(0, 0, 0, 0);
            } else {
                if (kk < K) {
                    const float* p;
                    if (ASRC == 0) {
                        p = Af + (size_t)(bm + row) * K + kk;
                    } else {
                        int node = (kk < OUT_) ? nodeS : nodeD;
                        int kc   = (kk < OUT_) ? kk : kk - OUT_;
                        p = featb + (size_t)node * OUT_ + kc;
                    }
                    float4 v0 = *(const float4*)p;
                    float4 v1 = *(const float4*)(p + 4);
                    wv.x = pack2(v0.x, v0.y); wv.y = pack2(v0.z, v0.w);
                    wv.z = pack2(v1.x, v1.y); wv.w = pack2(v1.z, v1.w);
                } else {
                    wv = make_uint4(0, 0, 0, 0);
                }
            }
            *(uint4*)((char*)As + row * 144 + half * 64 + c * 16) = wv;
        }
        // ---- stage B (transposed weights): Bs[n][k], n = bn+row
        {
            int n = bn + row;
            #pragma unroll
            for (int c = 0; c < 4; ++c) {
                int kk = k0 + half * 32 + c * 8;
                uint4 wv = (n < N && kk < K)
                    ? *(const uint4*)(Wt + (size_t)n * K + kk)
                    : make_uint4(0, 0, 0, 0);
                *(uint4*)((char*)Bs + row * 144 + half * 64 + c * 16) = wv;
            }
        }
        __syncthreads();
        // ---- 2 k-steps of 32, 16 MFMAs each
        #pragma unroll
        for (int kh = 0; kh < 2; ++kh) {
            bf16x8 af[4], bf[4];
            #pragma unroll
            for (int t = 0; t < 4; ++t)
                af[t] = *(const bf16x8*)((const char*)As +
                        (wm + t * 16 + lm) * 144 + kh * 64 + lq * 16);
            #pragma unroll
            for (int u = 0; u < 4; ++u)
                bf[u] = *(const bf16x8*)((const char*)Bs +
                        (wn + u * 16 + lm) * 144 + kh * 64 + lq * 16);
            #pragma unroll
            for (int t = 0; t < 4; ++t)
                #pragma unroll
                for (int u = 0; u < 4; ++u)
                    acc[t][u] = __builtin_amdgcn_mfma_f32_16x16x32_bf16(
                        af[t], bf[u], acc[t][u], 0, 0, 0);
        }
        __syncthreads();
    }

    // ---- epilogue: C col = lane&15, row = quad*4 + reg (verified m89/m91)
    #pragma unroll
    for (int u = 0; u < 4; ++u) {
        int col = bn + wn + u * 16 + lm;
        if (col >= N) continue;
        float bv = HAS_BIAS ? bias[col] : 0.f;
        #pragma unroll
        for (int t = 0; t < 4; ++t) {
            #pragma unroll
            for (int r = 0; r < 4; ++r) {
                int rowg = bm + wm + t * 16 + lq * 4 + r;
                float v = acc[t][u][r] + bv;
                if (DO_GELU) v = gelu_f(v);
                if (OUT_F32) Cf[(size_t)rowg * N + col] = v;
                else         Cb[(size_t)rowg * N + col] = f2u(v);
            }
        }
    }
}

// ---------------------------------------------------------------------------
// Attention scores: a_s[n,h] = sum_f wh[n,h*200+f]*att_src[h*200+f]; same a_d.
// ---------------------------------------------------------------------------
__global__ __launch_bounds__(256)
void scores_k(const u16* __restrict__ wh, const float* __restrict__ att_s,
              const float* __restrict__ att_d, float* __restrict__ a_s,
              float* __restrict__ a_d)
{
    int n = blockIdx.x * 4 + (threadIdx.x >> 6);
    int lane = threadIdx.x & 63;
    const u16* row = wh + (size_t)n * OUT_;
    float as0 = 0, as1 = 0, ad0 = 0, ad1 = 0;
    for (int f = lane; f < OUT_; f += 64) {
        float v = u2f(row[f]);
        float s = att_s[f];
        float d = att_d[f];
        if (f < 200) { as0 += v * s; ad0 += v * d; }
        else         { as1 += v * s; ad1 += v * d; }
    }
    for (int off = 32; off; off >>= 1) {
        as0 += __shfl_xor(as0, off); as1 += __shfl_xor(as1, off);
        ad0 += __shfl_xor(ad0, off); ad1 += __shfl_xor(ad1, off);
    }
    if (lane == 0) {
        a_s[(size_t)n * 2 + 0] = as0; a_s[(size_t)n * 2 + 1] = as1;
        a_d[(size_t)n * 2 + 0] = ad0; a_d[(size_t)n * 2 + 1] = ad1;
    }
}

// ---------------------------------------------------------------------------
// CSR build (edges shared across batches; incl. self-loops)
// ---------------------------------------------------------------------------
__global__ void csr_count_k(const int* __restrict__ edges, int* __restrict__ deg)
{
    int et = blockIdx.x * blockDim.x + threadIdx.x;
    if (et >= ET_) return;
    int dst = (et < E_) ? edges[E_ + et] : (et - E_);
    atomicAdd(&deg[dst], 1);
}

__global__ __launch_bounds__(1024)
void csr_scan_k(const int* __restrict__ deg, int* __restrict__ row_ptr,
                int* __restrict__ cnt)
{
    __shared__ int s[1024];
    int t = threadIdx.x;
    int d = deg[t];
    s[t] = d;
    __syncthreads();
    for (int off = 1; off < 1024; off <<= 1) {
        int v = (t >= off) ? s[t - off] : 0;
        __syncthreads();
        s[t] += v;
        __syncthreads();
    }
    row_ptr[t] = s[t] - d;   // exclusive
    cnt[t] = s[t] - d;
    if (t == 1023) row_ptr[1024] = s[t];
}

__global__ void csr_fill_k(const int* __restrict__ edges, int* __restrict__ cnt,
                           int* __restrict__ col_src)
{
    int et = blockIdx.x * blockDim.x + threadIdx.x;
    if (et >= ET_) return;
    int src, dst;
    if (et < E_) { src = edges[et]; dst = edges[E_ + et]; }
    else         { src = et - E_;  dst = src; }
    int pos = atomicAdd(&cnt[dst], 1);
    col_src[pos] = src;
}

// ---------------------------------------------------------------------------
// Fused GAT softmax + aggregation + residual, in place on f32 feat (d_out).
// feat = enc + segsum(coef * wh[src]) + gat_b. One block per (b, node).
// ---------------------------------------------------------------------------
__global__ __launch_bounds__(256)
void gat_k(const u16* __restrict__ wh,
           const float* __restrict__ a_s, const float* __restrict__ a_d,
           const int* __restrict__ row_ptr, const int* __restrict__ col_src,
           const float* __restrict__ gat_b, float* __restrict__ feat)
{
    int gn = blockIdx.x;                  // b*1024 + n
    int b = gn >> 10, n = gn & 1023;
    int tid = threadIdx.x;
    __shared__ float s_ee[2][MAXD];
    __shared__ int   s_src[MAXD];
    __shared__ float s_misc[6];           // m0,m1,invz0,invz1,ad0,ad1
    int start = row_ptr[n];
    int deg = row_ptr[n + 1] - start;

    if (tid < 64) {
        int lane = tid;
        float ad0 = a_d[(size_t)gn * 2 + 0];
        float ad1 = a_d[(size_t)gn * 2 + 1];
        float m0 = -1e30f, m1 = -1e30f;
        for (int j = lane; j < deg; j += 64) {
            int gs = (b << 10) + col_src[start + j];
            float e0 = a_s[(size_t)gs * 2 + 0] + ad0; e0 = (e0 > 0.f) ? e0 : 0.2f * e0;
            float e1 = a_s[(size_t)gs * 2 + 1] + ad1; e1 = (e1 > 0.f) ? e1 : 0.2f * e1;
            if (j < MAXD) { s_ee[0][j] = e0; s_ee[1][j] = e1; s_src[j] = gs; }
            m0 = fmaxf(m0, e0); m1 = fmaxf(m1, e1);
        }
        for (int off = 32; off; off >>= 1) {
            m0 = fmaxf(m0, __shfl_xor(m0, off));
            m1 = fmaxf(m1, __shfl_xor(m1, off));
        }
        float z0 = 0.f, z1 = 0.f;
        for (int j = lane; j < deg; j += 64) {
            float e0, e1;
            if (j < MAXD) { e0 = s_ee[0][j]; e1 = s_ee[1][j]; }
            else {
                int gs = (b << 10) + col_src[start + j];
                e0 = a_s[(size_t)gs * 2 + 0] + ad0; e0 = (e0 > 0.f) ? e0 : 0.2f * e0;
                e1 = a_s[(size_t)gs * 2 + 1] + ad1; e1 = (e1 > 0.f) ? e1 : 0.2f * e1;
            }
            float t0 = __expf(e0 - m0), t1 = __expf(e1 - m1);
            if (j < MAXD) { s_ee[0][j] = t0; s_ee[1][j] = t1; }
            z0 += t0; z1 += t1;
        }
        for (int off = 32; off; off >>= 1) {
            z0 += __shfl_xor(z0, off);
            z1 += __shfl_xor(z1, off);
        }
        if (lane == 0) {
            s_misc[0] = m0; s_misc[1] = m1;
            s_misc[2] = (z0 > 0.f) ? 1.f / z0 : 0.f;
            s_misc[3] = (z1 > 0.f) ? 1.f / z1 : 0.f;
            s_misc[4] = ad0; s_misc[5] = ad1;
        }
    }
    __syncthreads();
    float m0 = s_misc[0], m1 = s_misc[1];
    float iz0 = s_misc[2], iz1 = s_misc[3];
    float ad0 = s_misc[4], ad1 = s_misc[5];
    for (int c = tid; c < OUT_; c += 256) {
        int h = (c >= 200);
        float acc = 0.f;
        for (int j = 0; j < deg; ++j) {
            float w; int gs;
            if (j < MAXD) { w = s_ee[h][j]; gs = s_src[j]; }
            else {
                gs = (b << 10) + col_src[start + j];
                float e = a_s[(size_t)gs * 2 + h] + (h ? ad1 : ad0);
                e = (e > 0.f) ? e : 0.2f * e;
                w = __expf(e - (h ? m1 : m0));
            }
            acc += w * u2f(wh[(size_t)gs * OUT_ + c]);
        }
        acc *= (h ? iz1 : iz0);
        feat[(size_t)gn * OUT_ + c] += acc + gat_b[c];   // enc already there
    }
}

// ---------------------------------------------------------------------------
// Final tiny GEMM: pred[e,0:3] = p2[e,:] @ w3[400,3] + b3. One wave per edge.
// ---------------------------------------------------------------------------
__global__ __launch_bounds__(64)
void head3_k(const u16* __restrict__ p2, const float* __restrict__ w3,
             const float* __restrict__ b3, float* __restrict__ out, int row_base)
{
    int e = blockIdx.x;
    int lane = threadIdx.x;
    const u16* row = p2 + (size_t)e * OUT_;
    float s0 = 0, s1 = 0, s2 = 0;
    for (int k = lane; k < OUT_; k += 64) {
        float v = u2f(row[k]);
        s0 += v * w3[k * 3 + 0];
        s1 += v * w3[k * 3 + 1];
        s2 += v * w3[k * 3 + 2];
    }
    for (int off = 32; off; off >>= 1) {
        s0 += __shfl_xor(s0, off);
        s1 += __shfl_xor(s1, off);
        s2 += __shfl_xor(s2, off);
    }
    if (lane == 0) {
        size_t o = (size_t)FEAT_ELEMS + (size_t)(row_base + e) * 3;
        out[o + 0] = s0 + b3[0];
        out[o + 1] = s1 + b3[1];
        out[o + 2] = s2 + b3[2];
    }
}

extern "C" void kernel_launch(void* const* d_in, const int* in_sizes, int n_in,
                              void* d_out, int out_size, void* d_ws, size_t ws_size,
                              hipStream_t stream)
{
    const float* patch  = (const float*)d_in[0];
    const int*   edges  = (const int*)d_in[1];
    const float* enc_w1 = (const float*)d_in[2];
    const float* enc_b1 = (const float*)d_in[3];
    const float* enc_w2 = (const float*)d_in[4];
    const float* enc_b2 = (const float*)d_in[5];
    const float* gat_w  = (const float*)d_in[6];
    const float* att_s  = (const float*)d_in[7];
    const float* att_d  = (const float*)d_in[8];
    const float* gat_b  = (const float*)d_in[9];
    const float* h_w1   = (const float*)d_in[10];
    const float* h_b1   = (const float*)d_in[11];
    const float* h_w2   = (const float*)d_in[12];
    const float* h_b2   = (const float*)d_in[13];
    const float* h_w3   = (const float*)d_in[14];
    const float* h_b3   = (const float*)d_in[15];
    float* out = (float*)d_out;

    // workspace — peak 41.9 MB (< 60.4 MB proven-safe).
    // Region 0 (0..33.5M): enc1 (phase A) -> whb (B,C) -> p1 (D)
    // p2 (26.2M..39.3M, phase D) overlaps enc1 tail + w1t/w2t/gwt (all dead).
    char* ws = (char*)d_ws;
    u16* enc1 = (u16*)ws;                      // [32768,512] bf16
    u16* whb  = (u16*)ws;                      // [32768,400] bf16
    u16* p1   = (u16*)ws;                      // [16384,800] bf16
    u16* p2   = (u16*)(ws + 26214400);         // [16384,400] bf16
    u16* w1t  = (u16*)(ws + 33554432);         // [512,768]  (phase A only)
    u16* w2t  = (u16*)(ws + 34340864);         // [400,512]  (phase A only)
    u16* gwt  = (u16*)(ws + 34750464);         // [400,400]  (phase B only)
    u16* hw1t = (u16*)(ws + 39321600);         // [800,800]  (phase D)
    u16* hw2t = (u16*)(ws + 40601600);         // [400,800]  (phase D)
    float* a_s = (float*)(ws + 41241600);      // 65,536 f32
    float* a_d = (float*)(ws + 41503744);      // 65,536 f32
    int* deg     = (int*)(ws + 41765888);      // 1024
    int* row_ptr = deg + 1024;                 // 1025 (pad 1032)
    int* cnt     = row_ptr + 1032;             // 1024
    int* col_src = cnt + 1024;                 // 17,408 (end ≈ 41.85 MB)

    const int* src0 = edges;
    const int* dst0 = edges + E_;
    float* feat = out;                         // f32 [32768,400] in d_out

    // weight transposes (bf16), tiny
    wt_k<<<(HID * IN_DIM + 255) / 256, 256, 0, stream>>>(enc_w1, w1t, IN_DIM, HID);
    wt_k<<<(OUT_ * HID + 255) / 256, 256, 0, stream>>>(enc_w2, w2t, HID, OUT_);
    wt_k<<<(OUT_ * OUT_ + 255) / 256, 256, 0, stream>>>(gat_w, gwt, OUT_, OUT_);
    wt_k<<<(PAIR_ * PAIR_ + 255) / 256, 256, 0, stream>>>(h_w1, hw1t, PAIR_, PAIR_);
    wt_k<<<(OUT_ * PAIR_ + 255) / 256, 256, 0, stream>>>(h_w2, hw2t, PAIR_, OUT_);

    // CSR by dst (batch-independent)
    hipMemsetAsync(deg, 0, 1024 * sizeof(int), stream);
    csr_count_k<<<(ET_ + 255) / 256, 256, 0, stream>>>(edges, deg);
    csr_scan_k<<<1, 1024, 0, stream>>>(deg, row_ptr, cnt);
    csr_fill_k<<<(ET_ + 255) / 256, 256, 0, stream>>>(edges, cnt, col_src);

    // encoder: enc1 = gelu(patch @ w1 + b1);  feat(d_out,f32) = enc1 @ w2 + b2
    mfma_gemm_k<0, true, true, false><<<dim3(HID / 128, (B_ * N_) / 128), 256, 0, stream>>>(
        patch, nullptr, w1t, enc_b1, enc1, nullptr, B_ * N_, HID, IN_DIM,
        nullptr, nullptr, nullptr);
    mfma_gemm_k<1, false, true, true><<<dim3((OUT_ + 127) / 128, (B_ * N_) / 128), 256, 0, stream>>>(
        nullptr, enc1, w2t, enc_b2, nullptr, feat, B_ * N_, OUT_, HID,
        nullptr, nullptr, nullptr);

    // GAT linear: wh = enc(feat f32) @ gat_w  (whb overlays dead enc1)
    mfma_gemm_k<0, false, false, false><<<dim3((OUT_ + 127) / 128, (B_ * N_) / 128), 256, 0, stream>>>(
        feat, nullptr, gwt, nullptr, whb, nullptr, B_ * N_, OUT_, OUT_,
        nullptr, nullptr, nullptr);

    scores_k<<<(B_ * N_) / 4, 256, 0, stream>>>(whb, att_s, att_d, a_s, a_d);
    gat_k<<<B_ * N_, 256, 0, stream>>>(whb, a_s, a_d, row_ptr, col_src, gat_b, feat);

    // predict head, per batch (pair-gather from f32 feat in d_out)
    for (int b = 0; b < B_; ++b) {
        const float* featb = feat + (size_t)b * N_ * OUT_;
        mfma_gemm_k<2, true, true, false><<<dim3((PAIR_ + 127) / 128, E_ / 128), 256, 0, stream>>>(
            nullptr, nullptr, hw1t, h_b1, p1, nullptr, E_, PAIR_, PAIR_,
            featb, src0, dst0);
        mfma_gemm_k<1, true, true, false><<<dim3((OUT_ + 127) / 128, E_ / 128), 256, 0, stream>>>(
            nullptr, p1, hw2t, h_b2, p2, nullptr, E_, OUT_, PAIR_,
            nullptr, nullptr, nullptr);
        head3_k<<<E_, 64, 0, stream>>>(p2, h_w3, h_b3, out, b * E_);
    }
}

// Round 6
// 4177.197 us; speedup vs baseline: 4.1501x; 1.5089x over previous
//
#include <hip/hip_runtime.h>
#include <hip/hip_bf16.h>

typedef unsigned short u16;   // bf16 bits
typedef __attribute__((ext_vector_type(8))) short bf16x8;   // MFMA A/B frag
typedef __attribute__((ext_vector_type(4))) float f32x4;    // MFMA C/D frag

#define B_   32
#define N_   1024
#define E_   16384
#define ET_  17408            // E_ + N_ self-loops
#define IN_DIM 768
#define HID  512
#define OUT_ 400
#define PAIR_ 800
#define FEAT_ELEMS 13107200   // B_*N_*OUT_
#define MAXD 128

__device__ __forceinline__ float u2f(u16 u) {
    union { unsigned int i; float f; } v; v.i = ((unsigned int)u) << 16; return v.f;
}
__device__ __forceinline__ u16 f2u(float f) {
    __hip_bfloat16 h = __float2bfloat16(f);   // RNE, HW cvt on gfx950
    return *(u16*)&h;
}
__device__ __forceinline__ unsigned int pack2(float a, float b) {
    return (unsigned int)f2u(a) | ((unsigned int)f2u(b) << 16);
}

__device__ __forceinline__ float gelu_f(float x) {
    const float c = 0.7978845608028654f;          // sqrt(2/pi)
    float u = c * (x + 0.044715f * x * x * x);
    float t = 2.0f / (1.0f + __expf(-2.0f * u)) - 1.0f;   // tanh(u), overflow-safe
    return 0.5f * x * (1.0f + t);
}

// ---------------------------------------------------------------------------
// Weight transpose + bf16 convert: Wt[n][k] = bf16(W[k][n]). Tiny, once/launch.
// ---------------------------------------------------------------------------
__global__ void wt_k(const float* __restrict__ W, u16* __restrict__ Wt,
                     int K, int N)
{
    int i = blockIdx.x * 256 + threadIdx.x;
    if (i >= N * K) return;
    int n = i / K, k = i - n * K;
    Wt[i] = f2u(W[(size_t)k * N + n]);
}

// ---------------------------------------------------------------------------
// MFMA GEMM: C[M,N] = act(A[M,K] @ W[K,N] + bias), f32 accumulate.
// Tile 128x128, BK=64; 4 waves, each 64x64 via 4x4 grid of 16x16x32 MFMAs.
// Wt pre-transposed bf16 [N][K]. ASRC: 0 = f32 A; 1 = bf16 A;
// 2 = batched bf16 pair-gather: global row r -> batch b0+(r>>14), edge r&16383,
//     A row = concat(featb16[bn+src], featb16[bn+dst]) (uint4 loads);
// 3 = per-batch f32 pair-gather from featf (compact-ws fallback).
// M % 128 == 0; K % 8 == 0; N guarded. LDS pitch 72 elems: b128 reads land
// uniform 2-way on banks (free per m136).
// ---------------------------------------------------------------------------
template<int ASRC, bool DO_GELU, bool HAS_BIAS, bool OUT_F32>
__global__ __launch_bounds__(256)
void mfma_gemm_k(const float* __restrict__ Af, const u16* __restrict__ Ab,
                 const u16* __restrict__ Wt, const float* __restrict__ bias,
                 u16* __restrict__ Cb, float* __restrict__ Cf,
                 int M, int N, int K,
                 const float* __restrict__ featf, const u16* __restrict__ featb,
                 const int* __restrict__ src0, const int* __restrict__ dst0,
                 int b0)
{
    __shared__ __align__(16) u16 As[128 * 72];
    __shared__ __align__(16) u16 Bs[128 * 72];
    const int tid  = threadIdx.x;
    const int bm   = blockIdx.y * 128;
    const int bn   = blockIdx.x * 128;
    const int row  = tid >> 1;        // 0..127 (staging row)
    const int half = tid & 1;         // 32-elem k-half (staging)
    const int wave = tid >> 6;
    const int lane = tid & 63;
    const int wm   = (wave >> 1) * 64;
    const int wn   = (wave & 1) * 64;
    const int lm   = lane & 15;
    const int lq   = lane >> 4;

    int nodeS = 0, nodeD = 0;
    if (ASRC == 2) {
        int r = bm + row;
        int b = b0 + (r >> 14), e = r & 16383;
        nodeS = (b << 10) + src0[e];
        nodeD = (b << 10) + dst0[e];
    } else if (ASRC == 3) {
        int e = bm + row;
        nodeS = src0[e]; nodeD = dst0[e];
    }

    f32x4 acc[4][4] = {};

    for (int k0 = 0; k0 < K; k0 += 64) {
        // ---- stage A: [128][64] bf16; this thread: row, 32-elem k-half
        #pragma unroll
        for (int c = 0; c < 4; ++c) {
            int kk = k0 + half * 32 + c * 8;
            uint4 wv;
            if (ASRC == 1) {
                wv = (kk < K) ? *(const uint4*)(Ab + (size_t)(bm + row) * K + kk)
                              : make_uint4(0, 0, 0, 0);
            } else if (ASRC == 2) {
                if (kk < K) {
                    int node = (kk < OUT_) ? nodeS : nodeD;
                    int kc   = (kk < OUT_) ? kk : kk - OUT_;
                    wv = *(const uint4*)(featb + (size_t)node * OUT_ + kc);
                } else wv = make_uint4(0, 0, 0, 0);
            } else {
                if (kk < K) {
                    const float* p;
                    if (ASRC == 0) {
                        p = Af + (size_t)(bm + row) * K + kk;
                    } else {
                        int node = (kk < OUT_) ? nodeS : nodeD;
                        int kc   = (kk < OUT_) ? kk : kk - OUT_;
                        p = featf + (size_t)node * OUT_ + kc;
                    }
                    float4 v0 = *(const float4*)p;
                    float4 v1 = *(const float4*)(p + 4);
                    wv.x = pack2(v0.x, v0.y); wv.y = pack2(v0.z, v0.w);
                    wv.z = pack2(v1.x, v1.y); wv.w = pack2(v1.z, v1.w);
                } else wv = make_uint4(0, 0, 0, 0);
            }
            *(uint4*)((char*)As + row * 144 + half * 64 + c * 16) = wv;
        }
        // ---- stage B (transposed weights): Bs[n][k]
        {
            int n = bn + row;
            #pragma unroll
            for (int c = 0; c < 4; ++c) {
                int kk = k0 + half * 32 + c * 8;
                uint4 wv = (n < N && kk < K)
                    ? *(const uint4*)(Wt + (size_t)n * K + kk)
                    : make_uint4(0, 0, 0, 0);
                *(uint4*)((char*)Bs + row * 144 + half * 64 + c * 16) = wv;
            }
        }
        __syncthreads();
        #pragma unroll
        for (int kh = 0; kh < 2; ++kh) {
            bf16x8 af[4], bfr[4];
            #pragma unroll
            for (int t = 0; t < 4; ++t)
                af[t] = *(const bf16x8*)((const char*)As +
                        (wm + t * 16 + lm) * 144 + kh * 64 + lq * 16);
            #pragma unroll
            for (int u = 0; u < 4; ++u)
                bfr[u] = *(const bf16x8*)((const char*)Bs +
                        (wn + u * 16 + lm) * 144 + kh * 64 + lq * 16);
            #pragma unroll
            for (int t = 0; t < 4; ++t)
                #pragma unroll
                for (int u = 0; u < 4; ++u)
                    acc[t][u] = __builtin_amdgcn_mfma_f32_16x16x32_bf16(
                        af[t], bfr[u], acc[t][u], 0, 0, 0);
        }
        __syncthreads();
    }

    // ---- epilogue: C col = lane&15, row = quad*4 + reg (verified m89/m91)
    #pragma unroll
    for (int u = 0; u < 4; ++u) {
        int col = bn + wn + u * 16 + lm;
        if (col >= N) continue;
        float bv = HAS_BIAS ? bias[col] : 0.f;
        #pragma unroll
        for (int t = 0; t < 4; ++t) {
            #pragma unroll
            for (int r = 0; r < 4; ++r) {
                int rowg = bm + wm + t * 16 + lq * 4 + r;
                float v = acc[t][u][r] + bv;
                if (DO_GELU) v = gelu_f(v);
                if (OUT_F32) Cf[(size_t)rowg * N + col] = v;
                else         Cb[(size_t)rowg * N + col] = f2u(v);
            }
        }
    }
}

// ---------------------------------------------------------------------------
// Attention scores: a_s[n,h] = sum_f wh[n,h*200+f]*att_src[h*200+f]; same a_d.
// ---------------------------------------------------------------------------
__global__ __launch_bounds__(256)
void scores_k(const u16* __restrict__ wh, const float* __restrict__ att_s,
              const float* __restrict__ att_d, float* __restrict__ a_s,
              float* __restrict__ a_d)
{
    int n = blockIdx.x * 4 + (threadIdx.x >> 6);
    int lane = threadIdx.x & 63;
    const u16* row = wh + (size_t)n * OUT_;
    float as0 = 0, as1 = 0, ad0 = 0, ad1 = 0;
    for (int f = lane; f < OUT_; f += 64) {
        float v = u2f(row[f]);
        float s = att_s[f];
        float d = att_d[f];
        if (f < 200) { as0 += v * s; ad0 += v * d; }
        else         { as1 += v * s; ad1 += v * d; }
    }
    for (int off = 32; off; off >>= 1) {
        as0 += __shfl_xor(as0, off); as1 += __shfl_xor(as1, off);
        ad0 += __shfl_xor(ad0, off); ad1 += __shfl_xor(ad1, off);
    }
    if (lane == 0) {
        a_s[(size_t)n * 2 + 0] = as0; a_s[(size_t)n * 2 + 1] = as1;
        a_d[(size_t)n * 2 + 0] = ad0; a_d[(size_t)n * 2 + 1] = ad1;
    }
}

// ---------------------------------------------------------------------------
// CSR build (edges shared across batches; incl. self-loops)
// ---------------------------------------------------------------------------
__global__ void csr_count_k(const int* __restrict__ edges, int* __restrict__ deg)
{
    int et = blockIdx.x * blockDim.x + threadIdx.x;
    if (et >= ET_) return;
    int dst = (et < E_) ? edges[E_ + et] : (et - E_);
    atomicAdd(&deg[dst], 1);
}

__global__ __launch_bounds__(1024)
void csr_scan_k(const int* __restrict__ deg, int* __restrict__ row_ptr,
                int* __restrict__ cnt)
{
    __shared__ int s[1024];
    int t = threadIdx.x;
    int d = deg[t];
    s[t] = d;
    __syncthreads();
    for (int off = 1; off < 1024; off <<= 1) {
        int v = (t >= off) ? s[t - off] : 0;
        __syncthreads();
        s[t] += v;
        __syncthreads();
    }
    row_ptr[t] = s[t] - d;   // exclusive
    cnt[t] = s[t] - d;
    if (t == 1023) row_ptr[1024] = s[t];
}

__global__ void csr_fill_k(const int* __restrict__ edges, int* __restrict__ cnt,
                           int* __restrict__ col_src)
{
    int et = blockIdx.x * blockDim.x + threadIdx.x;
    if (et >= ET_) return;
    int src, dst;
    if (et < E_) { src = edges[et]; dst = edges[E_ + et]; }
    else         { src = et - E_;  dst = src; }
    int pos = atomicAdd(&cnt[dst], 1);
    col_src[pos] = src;
}

// ---------------------------------------------------------------------------
// Fused GAT softmax + aggregation + residual, in place on f32 feat (d_out).
// Vectorized: lane<50 handles 8 contiguous cols via uint4 wh loads; 4 j-slices
// (one per wave) reduced through padded LDS partials. Optionally emits bf16
// copy of feat (featb16) for the head gather.
// ---------------------------------------------------------------------------
__global__ __launch_bounds__(256)
void gat_k(const u16* __restrict__ wh,
           const float* __restrict__ a_s, const float* __restrict__ a_d,
           const int* __restrict__ row_ptr, const int* __restrict__ col_src,
           const float* __restrict__ gat_b, float* __restrict__ feat,
           u16* __restrict__ featb16)
{
    int gn = blockIdx.x;                  // b*1024 + n
    int b = gn >> 10, n = gn & 1023;
    int tid = threadIdx.x;
    __shared__ float s_ee[2][MAXD];
    __shared__ int   s_src[MAXD];
    __shared__ float s_misc[6];           // m0,m1,invz0,invz1,ad0,ad1
    __shared__ float s_part[4][50][9];    // +1 pad col: spread banks
    int start = row_ptr[n];
    int deg = row_ptr[n + 1] - start;

    if (tid < 64) {
        int lane = tid;
        float ad0 = a_d[(size_t)gn * 2 + 0];
        float ad1 = a_d[(size_t)gn * 2 + 1];
        float m0 = -1e30f, m1 = -1e30f;
        for (int j = lane; j < deg; j += 64) {
            int gs = (b << 10) + col_src[start + j];
            float e0 = a_s[(size_t)gs * 2 + 0] + ad0; e0 = (e0 > 0.f) ? e0 : 0.2f * e0;
            float e1 = a_s[(size_t)gs * 2 + 1] + ad1; e1 = (e1 > 0.f) ? e1 : 0.2f * e1;
            if (j < MAXD) { s_ee[0][j] = e0; s_ee[1][j] = e1; s_src[j] = gs; }
            m0 = fmaxf(m0, e0); m1 = fmaxf(m1, e1);
        }
        for (int off = 32; off; off >>= 1) {
            m0 = fmaxf(m0, __shfl_xor(m0, off));
            m1 = fmaxf(m1, __shfl_xor(m1, off));
        }
        float z0 = 0.f, z1 = 0.f;
        for (int j = lane; j < deg; j += 64) {
            float e0, e1;
            if (j < MAXD) { e0 = s_ee[0][j]; e1 = s_ee[1][j]; }
            else {
                int gs = (b << 10) + col_src[start + j];
                e0 = a_s[(size_t)gs * 2 + 0] + ad0; e0 = (e0 > 0.f) ? e0 : 0.2f * e0;
                e1 = a_s[(size_t)gs * 2 + 1] + ad1; e1 = (e1 > 0.f) ? e1 : 0.2f * e1;
            }
            float t0 = __expf(e0 - m0), t1 = __expf(e1 - m1);
            if (j < MAXD) { s_ee[0][j] = t0; s_ee[1][j] = t1; }
            z0 += t0; z1 += t1;
        }
        for (int off = 32; off; off >>= 1) {
            z0 += __shfl_xor(z0, off);
            z1 += __shfl_xor(z1, off);
        }
        if (lane == 0) {
            s_misc[0] = m0; s_misc[1] = m1;
            s_misc[2] = (z0 > 0.f) ? 1.f / z0 : 0.f;
            s_misc[3] = (z1 > 0.f) ? 1.f / z1 : 0.f;
            s_misc[4] = ad0; s_misc[5] = ad1;
        }
    }
    __syncthreads();

    int wv = tid >> 6, ln = tid & 63;
    if (ln < 50) {
        int h = (ln >= 25);
        float m = s_misc[h], ad = s_misc[4 + h];
        float acc[8] = {};
        for (int j = wv; j < deg; j += 4) {
            float w; int gs;
            if (j < MAXD) { w = s_ee[h][j]; gs = s_src[j]; }
            else {
                gs = (b << 10) + col_src[start + j];
                float e = a_s[(size_t)gs * 2 + h] + ad;
                e = (e > 0.f) ? e : 0.2f * e;
                w = __expf(e - m);
            }
            uint4 q = *(const uint4*)(wh + (size_t)gs * OUT_ + ln * 8);
            acc[0] += w * u2f((u16)(q.x & 0xffff));
            acc[1] += w * u2f((u16)(q.x >> 16));
            acc[2] += w * u2f((u16)(q.y & 0xffff));
            acc[3] += w * u2f((u16)(q.y >> 16));
            acc[4] += w * u2f((u16)(q.z & 0xffff));
            acc[5] += w * u2f((u16)(q.z >> 16));
            acc[6] += w * u2f((u16)(q.w & 0xffff));
            acc[7] += w * u2f((u16)(q.w >> 16));
        }
        #pragma unroll
        for (int k = 0; k < 8; ++k) s_part[wv][ln][k] = acc[k];
    }
    __syncthreads();
    if (tid < 50) {
        int h = (tid >= 25);
        float iz = s_misc[2 + h];
        size_t base = (size_t)gn * OUT_ + tid * 8;
        float4 f0 = *(const float4*)(feat + base);
        float4 f1 = *(const float4*)(feat + base + 4);
        float fv[8] = { f0.x, f0.y, f0.z, f0.w, f1.x, f1.y, f1.z, f1.w };
        float o[8];
        #pragma unroll
        for (int k = 0; k < 8; ++k) {
            float s = s_part[0][tid][k] + s_part[1][tid][k] +
                      s_part[2][tid][k] + s_part[3][tid][k];
            o[k] = fv[k] + s * iz + gat_b[tid * 8 + k];
        }
        *(float4*)(feat + base)     = make_float4(o[0], o[1], o[2], o[3]);
        *(float4*)(feat + base + 4) = make_float4(o[4], o[5], o[6], o[7]);
        if (featb16) {
            uint4 bq;
            bq.x = pack2(o[0], o[1]); bq.y = pack2(o[2], o[3]);
            bq.z = pack2(o[4], o[5]); bq.w = pack2(o[6], o[7]);
            *(uint4*)(featb16 + base) = bq;
        }
    }
}

// ---------------------------------------------------------------------------
// Final tiny GEMM: pred[e,:] = p2[e,:] @ w3[400,3] + b3.
// 4 waves/block, each wave does 4 edges; per-lane w3 slice held in registers.
// ---------------------------------------------------------------------------
__global__ __launch_bounds__(256)
void head3_k(const u16* __restrict__ p2, const float* __restrict__ w3,
             const float* __restrict__ b3, float* __restrict__ out,
             int row_base, int nrows)
{
    int wv = threadIdx.x >> 6, lane = threadIdx.x & 63;
    float w3r[24];
    if (lane < 50) {
        #pragma unroll
        for (int q = 0; q < 6; ++q) {
            float4 v = *(const float4*)(w3 + lane * 24 + q * 4);
            w3r[q * 4 + 0] = v.x; w3r[q * 4 + 1] = v.y;
            w3r[q * 4 + 2] = v.z; w3r[q * 4 + 3] = v.w;
        }
    }
    int e0 = blockIdx.x * 16 + wv * 4;
    for (int ei = 0; ei < 4; ++ei) {
        int e = e0 + ei;
        if (e >= nrows) break;
        float s0 = 0, s1 = 0, s2 = 0;
        if (lane < 50) {
            uint4 q = *(const uint4*)(p2 + (size_t)e * OUT_ + lane * 8);
            float f[8];
            f[0] = u2f((u16)(q.x & 0xffff)); f[1] = u2f((u16)(q.x >> 16));
            f[2] = u2f((u16)(q.y & 0xffff)); f[3] = u2f((u16)(q.y >> 16));
            f[4] = u2f((u16)(q.z & 0xffff)); f[5] = u2f((u16)(q.z >> 16));
            f[6] = u2f((u16)(q.w & 0xffff)); f[7] = u2f((u16)(q.w >> 16));
            #pragma unroll
            for (int k = 0; k < 8; ++k) {
                s0 += f[k] * w3r[k * 3 + 0];
                s1 += f[k] * w3r[k * 3 + 1];
                s2 += f[k] * w3r[k * 3 + 2];
            }
        }
        for (int off = 32; off; off >>= 1) {
            s0 += __shfl_xor(s0, off);
            s1 += __shfl_xor(s1, off);
            s2 += __shfl_xor(s2, off);
        }
        if (lane == 0) {
            size_t o = (size_t)FEAT_ELEMS + (size_t)(row_base + e) * 3;
            out[o + 0] = s0 + b3[0];
            out[o + 1] = s1 + b3[1];
            out[o + 2] = s2 + b3[2];
        }
    }
}

extern "C" void kernel_launch(void* const* d_in, const int* in_sizes, int n_in,
                              void* d_out, int out_size, void* d_ws, size_t ws_size,
                              hipStream_t stream)
{
    const float* patch  = (const float*)d_in[0];
    const int*   edges  = (const int*)d_in[1];
    const float* enc_w1 = (const float*)d_in[2];
    const float* enc_b1 = (const float*)d_in[3];
    const float* enc_w2 = (const float*)d_in[4];
    const float* enc_b2 = (const float*)d_in[5];
    const float* gat_w  = (const float*)d_in[6];
    const float* att_s  = (const float*)d_in[7];
    const float* att_d  = (const float*)d_in[8];
    const float* gat_b  = (const float*)d_in[9];
    const float* h_w1   = (const float*)d_in[10];
    const float* h_b1   = (const float*)d_in[11];
    const float* h_w2   = (const float*)d_in[12];
    const float* h_b2   = (const float*)d_in[13];
    const float* h_w3   = (const float*)d_in[14];
    const float* h_b3   = (const float*)d_in[15];
    float* out  = (float*)d_out;
    float* feat = out;                          // f32 [32768,400] in d_out
    char*  ws   = (char*)d_ws;

    const int* src0 = edges;
    const int* dst0 = edges + E_;

    // --- mode select from ws_size (deterministic; graph-capture safe) ------
    // BIG: [0,33.5M) enc1 (phase A) / featb16 (phase C+); chunkspace at 33.5M
    //      holds whb (B/C) then p1/p2 (head, CB batches); 4MB fixed tail.
    // SMALL: proven round-5 compact layout (41.9 MB), per-batch f32 gather.
    const size_t R0 = 33554432ull, TAIL = 4194304ull;
    const size_t PER_B = 39321600ull;           // p1 (26.2M) + p2 (13.1M)
    int CB = 0;
    if (ws_size > R0 + TAIL) {
        size_t avail = ws_size - R0 - TAIL;
        if (avail >= 26214400ull)               // whb must fit
            for (int c = 32; c >= 1; c >>= 1)
                if ((size_t)c * PER_B <= avail) { CB = c; break; }
    }
    const bool big = (CB >= 1);

    u16 *enc1, *whb, *p1, *p2, *featb16, *w1t, *w2t, *gwt, *hw1t, *hw2t;
    float *a_s, *a_d; int *deg, *row_ptr, *cnt, *col_src;
    if (big) {
        enc1    = (u16*)ws;
        featb16 = (u16*)ws;                     // overlays enc1 (dead)
        whb     = (u16*)(ws + R0);
        p1      = (u16*)(ws + R0);              // overlays whb (dead in head)
        p2      = (u16*)(ws + R0 + (size_t)CB * 26214400ull);
        size_t tb = (ws_size - TAIL) & ~(size_t)255;
        w1t  = (u16*)(ws + tb);
        w2t  = (u16*)(ws + tb + 786432);
        gwt  = (u16*)(ws + tb + 1196032);
        hw1t = (u16*)(ws + tb + 1516032);
        hw2t = (u16*)(ws + tb + 2796032);
        a_s  = (float*)(ws + tb + 3436032);
        a_d  = (float*)(ws + tb + 3698176);
        deg  = (int*)(ws + tb + 3960320);
    } else {
        enc1    = (u16*)ws;
        whb     = (u16*)ws;
        p1      = (u16*)ws;
        featb16 = nullptr;
        p2      = (u16*)(ws + 26214400);
        w1t  = (u16*)(ws + 33554432);
        w2t  = (u16*)(ws + 34340864);
        gwt  = (u16*)(ws + 34750464);
        hw1t = (u16*)(ws + 39321600);
        hw2t = (u16*)(ws + 40601600);
        a_s  = (float*)(ws + 41241600);
        a_d  = (float*)(ws + 41503744);
        deg  = (int*)(ws + 41765888);
    }
    row_ptr = deg + 1024;
    cnt     = row_ptr + 1032;
    col_src = cnt + 1024;

    // weight transposes (bf16), tiny
    wt_k<<<(HID * IN_DIM + 255) / 256, 256, 0, stream>>>(enc_w1, w1t, IN_DIM, HID);
    wt_k<<<(OUT_ * HID + 255) / 256, 256, 0, stream>>>(enc_w2, w2t, HID, OUT_);
    wt_k<<<(OUT_ * OUT_ + 255) / 256, 256, 0, stream>>>(gat_w, gwt, OUT_, OUT_);
    wt_k<<<(PAIR_ * PAIR_ + 255) / 256, 256, 0, stream>>>(h_w1, hw1t, PAIR_, PAIR_);
    wt_k<<<(OUT_ * PAIR_ + 255) / 256, 256, 0, stream>>>(h_w2, hw2t, PAIR_, OUT_);

    // CSR by dst (batch-independent)
    hipMemsetAsync(deg, 0, 1024 * sizeof(int), stream);
    csr_count_k<<<(ET_ + 255) / 256, 256, 0, stream>>>(edges, deg);
    csr_scan_k<<<1, 1024, 0, stream>>>(deg, row_ptr, cnt);
    csr_fill_k<<<(ET_ + 255) / 256, 256, 0, stream>>>(edges, cnt, col_src);

    // encoder: enc1 = gelu(patch @ w1 + b1);  feat(d_out,f32) = enc1 @ w2 + b2
    mfma_gemm_k<0, true, true, false><<<dim3(HID / 128, (B_ * N_) / 128), 256, 0, stream>>>(
        patch, nullptr, w1t, enc_b1, enc1, nullptr, B_ * N_, HID, IN_DIM,
        nullptr, nullptr, nullptr, nullptr, 0);
    mfma_gemm_k<1, false, true, true><<<dim3((OUT_ + 127) / 128, (B_ * N_) / 128), 256, 0, stream>>>(
        nullptr, enc1, w2t, enc_b2, nullptr, feat, B_ * N_, OUT_, HID,
        nullptr, nullptr, nullptr, nullptr, 0);

    // GAT linear: wh = enc(feat f32) @ gat_w
    mfma_gemm_k<0, false, false, false><<<dim3((OUT_ + 127) / 128, (B_ * N_) / 128), 256, 0, stream>>>(
        feat, nullptr, gwt, nullptr, whb, nullptr, B_ * N_, OUT_, OUT_,
        nullptr, nullptr, nullptr, nullptr, 0);

    scores_k<<<(B_ * N_) / 4, 256, 0, stream>>>(whb, att_s, att_d, a_s, a_d);
    gat_k<<<B_ * N_, 256, 0, stream>>>(whb, a_s, a_d, row_ptr, col_src,
                                       gat_b, feat, featb16);

    // predict head
    if (big) {
        for (int b0 = 0; b0 < B_; b0 += CB) {
            int Mr = CB * E_;
            mfma_gemm_k<2, true, true, false><<<dim3((PAIR_ + 127) / 128, Mr / 128), 256, 0, stream>>>(
                nullptr, nullptr, hw1t, h_b1, p1, nullptr, Mr, PAIR_, PAIR_,
                nullptr, featb16, src0, dst0, b0);
            mfma_gemm_k<1, true, true, false><<<dim3((OUT_ + 127) / 128, Mr / 128), 256, 0, stream>>>(
                nullptr, p1, hw2t, h_b2, p2, nullptr, Mr, OUT_, PAIR_,
                nullptr, nullptr, nullptr, nullptr, 0);
            head3_k<<<(Mr + 15) / 16, 256, 0, stream>>>(p2, h_w3, h_b3, out,
                                                        b0 * E_, Mr);
        }
    } else {
        for (int b = 0; b < B_; ++b) {
            const float* featb = feat + (size_t)b * N_ * OUT_;
            mfma_gemm_k<3, true, true, false><<<dim3((PAIR_ + 127) / 128, E_ / 128), 256, 0, stream>>>(
                nullptr, nullptr, hw1t, h_b1, p1, nullptr, E_, PAIR_, PAIR_,
                featb, nullptr, src0, dst0, 0);
            mfma_gemm_k<1, true, true, false><<<dim3((OUT_ + 127) / 128, E_ / 128), 256, 0, stream>>>(
                nullptr, p1, hw2t, h_b2, p2, nullptr, E_, OUT_, PAIR_,
                nullptr, nullptr, nullptr, nullptr, 0);
            head3_k<<<(E_ + 15) / 16, 256, 0, stream>>>(p2, h_w3, h_b3, out,
                                                        b * E_, E_);
        }
    }
}

// Round 7
// 2562.998 us; speedup vs baseline: 6.7639x; 1.6298x over previous
//
#include <hip/hip_runtime.h>
#include <hip/hip_bf16.h>

typedef unsigned short u16;   // bf16 bits
typedef __attribute__((ext_vector_type(8))) short bf16x8;   // MFMA A/B frag
typedef __attribute__((ext_vector_type(4))) float f32x4;    // MFMA C/D frag

#define B_   32
#define N_   1024
#define E_   16384
#define ET_  17408            // E_ + N_ self-loops
#define IN_DIM 768
#define HID  512
#define OUT_ 400
#define PAIR_ 800
#define FEAT_ELEMS 13107200   // B_*N_*OUT_
#define MAXD 128

__device__ __forceinline__ float u2f(u16 u) {
    union { unsigned int i; float f; } v; v.i = ((unsigned int)u) << 16; return v.f;
}
__device__ __forceinline__ u16 f2u(float f) {
    __hip_bfloat16 h = __float2bfloat16(f);   // RNE, HW cvt on gfx950
    return *(u16*)&h;
}
__device__ __forceinline__ unsigned int pack2(float a, float b) {
    return (unsigned int)f2u(a) | ((unsigned int)f2u(b) << 16);
}

__device__ __forceinline__ float gelu_f(float x) {
    const float c = 0.7978845608028654f;          // sqrt(2/pi)
    float u = c * (x + 0.044715f * x * x * x);
    float t = 2.0f / (1.0f + __expf(-2.0f * u)) - 1.0f;   // tanh(u), overflow-safe
    return 0.5f * x * (1.0f + t);
}

// async global->LDS, 16 B per lane; LDS dest is wave-uniform base + lane*16
__device__ __forceinline__ void load_lds16(const void* g, void* l) {
    __builtin_amdgcn_global_load_lds(
        (const __attribute__((address_space(1))) void*)g,
        (__attribute__((address_space(3))) void*)l, 16, 0, 0);
}

// ---------------------------------------------------------------------------
// Weight transpose + bf16 convert: Wt[n][k] = bf16(W[k][n]). Tiny, once/launch.
// ---------------------------------------------------------------------------
__global__ void wt_k(const float* __restrict__ W, u16* __restrict__ Wt,
                     int K, int N)
{
    int i = blockIdx.x * 256 + threadIdx.x;
    if (i >= N * K) return;
    int n = i / K, k = i - n * K;
    Wt[i] = f2u(W[(size_t)k * N + n]);
}

// ---------------------------------------------------------------------------
// MFMA GEMM: C[M,N] = act(A[M,K] @ W[K,N] + bias), f32 accumulate.
// Tile 128x128, BK=64; 4 waves, each 64x64 via 4x4 grid of 16x16x32 MFMAs.
// Wt pre-transposed bf16 [N][K].
// ASRC: 0 = f32 A (VGPR cvt staging); 1 = bf16 A (async global_load_lds);
//       2 = batched bf16 pair-gather (async), row r -> batch b0+(r>>14),
//           A row = concat(featb16[src], featb16[dst]);
//       3 = per-batch f32 pair-gather (VGPR staging fallback).
// LDS layout: unpadded pitch 128 B, XOR swizzle phys_chunk = log_chunk^(row&7)
// (16B chunks) -> global_load_lds lane-contiguity satisfied AND quarter-wave
// ds_read_b128 is uniform 2-way on banks (free, m136). OOB lanes read zbuf.
// ---------------------------------------------------------------------------
template<int ASRC, bool DO_GELU, bool HAS_BIAS, bool OUT_F32>
__global__ __launch_bounds__(256)
void mfma_gemm_k(const float* __restrict__ Af, const u16* __restrict__ Ab,
                 const u16* __restrict__ Wt, const float* __restrict__ bias,
                 u16* __restrict__ Cb, float* __restrict__ Cf,
                 int M, int N, int K,
                 const float* __restrict__ featf, const u16* __restrict__ featb,
                 const int* __restrict__ src0, const int* __restrict__ dst0,
                 int b0, const u16* __restrict__ zbuf)
{
    __shared__ __align__(16) u16 As[128 * 64];
    __shared__ __align__(16) u16 Bs[128 * 64];
    const int tid  = threadIdx.x;
    const int bm   = blockIdx.y * 128;
    const int bn   = blockIdx.x * 128;
    const int wave = tid >> 6;
    const int lane = tid & 63;
    const int wm   = (wave >> 1) * 64;
    const int wn   = (wave & 1) * 64;
    const int lm   = lane & 15;
    const int lq   = lane >> 4;
    const int lb   = lm & 7;
    // async-staging lane geometry: instr c4 covers rows w*32+c4*8 .. +7
    const int l8 = lane >> 3;            // row within 8-row group
    const int cl = (lane & 7) ^ l8;      // logical 8-elem chunk for this lane

    // per-c4 row metadata
    size_t arow[4]; int nS[4], nD[4]; size_t brow[4]; bool bok[4];
    #pragma unroll
    for (int c4 = 0; c4 < 4; ++c4) {
        int rt = wave * 32 + c4 * 8 + l8;          // tile row 0..127
        if (ASRC == 1) arow[c4] = (size_t)(bm + rt) * K;
        if (ASRC == 2) {
            int r = bm + rt;
            int b = b0 + (r >> 14), e = r & (E_ - 1);
            nS[c4] = (b << 10) + src0[e];
            nD[c4] = (b << 10) + dst0[e];
        }
        int n = bn + rt;
        bok[c4] = (n < N);
        brow[c4] = (size_t)(n < N ? n : 0) * K;
    }
    // VGPR-staging geometry (ASRC 0/3)
    const int vrow = tid >> 1, vhalf = tid & 1;
    int nodeS = 0, nodeD = 0;
    if (ASRC == 3) { int e = bm + vrow; nodeS = src0[e]; nodeD = dst0[e]; }

    f32x4 acc[4][4] = {};

    for (int k0 = 0; k0 < K; k0 += 64) {
        // ---- stage A
        if (ASRC == 1 || ASRC == 2) {
            int kk = k0 + cl * 8;
            #pragma unroll
            for (int c4 = 0; c4 < 4; ++c4) {
                const u16* ga;
                if (ASRC == 1) {
                    ga = (kk < K) ? Ab + arow[c4] + kk : zbuf;
                } else {
                    ga = (kk < OUT_)  ? featb + (size_t)nS[c4] * OUT_ + kk
                       : (kk < PAIR_) ? featb + (size_t)nD[c4] * OUT_ + (kk - OUT_)
                                      : zbuf;
                }
                load_lds16(ga, (char*)As + (wave * 32 + c4 * 8) * 128);
            }
        } else {
            #pragma unroll
            for (int c = 0; c < 4; ++c) {
                int c_log = vhalf * 4 + c;
                int kk = k0 + c_log * 8;
                uint4 wv = make_uint4(0, 0, 0, 0);
                if (kk < K) {
                    const float* p;
                    if (ASRC == 0) {
                        p = Af + (size_t)(bm + vrow) * K + kk;
                    } else {
                        int node = (kk < OUT_) ? nodeS : nodeD;
                        int kc   = (kk < OUT_) ? kk : kk - OUT_;
                        p = featf + (size_t)node * OUT_ + kc;
                    }
                    float4 v0 = *(const float4*)p;
                    float4 v1 = *(const float4*)(p + 4);
                    wv.x = pack2(v0.x, v0.y); wv.y = pack2(v0.z, v0.w);
                    wv.z = pack2(v1.x, v1.y); wv.w = pack2(v1.z, v1.w);
                }
                int pc = c_log ^ (vrow & 7);
                *(uint4*)((char*)As + vrow * 128 + pc * 16) = wv;
            }
        }
        // ---- stage B (always async; Wt bf16 [N][K])
        {
            int kk = k0 + cl * 8;
            #pragma unroll
            for (int c4 = 0; c4 < 4; ++c4) {
                const u16* gb = (bok[c4] && kk < K) ? Wt + brow[c4] + kk : zbuf;
                load_lds16(gb, (char*)Bs + (wave * 32 + c4 * 8) * 128);
            }
        }
        __syncthreads();
        #pragma unroll
        for (int kh = 0; kh < 2; ++kh) {
            bf16x8 af[4], bfr[4];
            #pragma unroll
            for (int t = 0; t < 4; ++t)
                af[t] = *(const bf16x8*)((const char*)As +
                        (wm + t * 16 + lm) * 128 + (((kh * 4 + lq) ^ lb) * 16));
            #pragma unroll
            for (int u = 0; u < 4; ++u)
                bfr[u] = *(const bf16x8*)((const char*)Bs +
                        (wn + u * 16 + lm) * 128 + (((kh * 4 + lq) ^ lb) * 16));
            #pragma unroll
            for (int t = 0; t < 4; ++t)
                #pragma unroll
                for (int u = 0; u < 4; ++u)
                    acc[t][u] = __builtin_amdgcn_mfma_f32_16x16x32_bf16(
                        af[t], bfr[u], acc[t][u], 0, 0, 0);
        }
        __syncthreads();
    }

    // ---- epilogue: C col = lane&15, row = quad*4 + reg (verified m89/m91)
    #pragma unroll
    for (int u = 0; u < 4; ++u) {
        int col = bn + wn + u * 16 + lm;
        if (col >= N) continue;
        float bv = HAS_BIAS ? bias[col] : 0.f;
        #pragma unroll
        for (int t = 0; t < 4; ++t) {
            #pragma unroll
            for (int r = 0; r < 4; ++r) {
                int rowg = bm + wm + t * 16 + lq * 4 + r;
                float v = acc[t][u][r] + bv;
                if (DO_GELU) v = gelu_f(v);
                if (OUT_F32) Cf[(size_t)rowg * N + col] = v;
                else         Cb[(size_t)rowg * N + col] = f2u(v);
            }
        }
    }
}

// ---------------------------------------------------------------------------
// Attention scores: a_s[n,h] = sum_f wh[n,h*200+f]*att_src[h*200+f]; same a_d.
// ---------------------------------------------------------------------------
__global__ __launch_bounds__(256)
void scores_k(const u16* __restrict__ wh, const float* __restrict__ att_s,
              const float* __restrict__ att_d, float* __restrict__ a_s,
              float* __restrict__ a_d)
{
    int n = blockIdx.x * 4 + (threadIdx.x >> 6);
    int lane = threadIdx.x & 63;
    const u16* row = wh + (size_t)n * OUT_;
    float as0 = 0, as1 = 0, ad0 = 0, ad1 = 0;
    for (int f = lane; f < OUT_; f += 64) {
        float v = u2f(row[f]);
        float s = att_s[f];
        float d = att_d[f];
        if (f < 200) { as0 += v * s; ad0 += v * d; }
        else         { as1 += v * s; ad1 += v * d; }
    }
    for (int off = 32; off; off >>= 1) {
        as0 += __shfl_xor(as0, off); as1 += __shfl_xor(as1, off);
        ad0 += __shfl_xor(ad0, off); ad1 += __shfl_xor(ad1, off);
    }
    if (lane == 0) {
        a_s[(size_t)n * 2 + 0] = as0; a_s[(size_t)n * 2 + 1] = as1;
        a_d[(size_t)n * 2 + 0] = ad0; a_d[(size_t)n * 2 + 1] = ad1;
    }
}

// ---------------------------------------------------------------------------
// CSR build (edges shared across batches; incl. self-loops)
// ---------------------------------------------------------------------------
__global__ void csr_count_k(const int* __restrict__ edges, int* __restrict__ deg)
{
    int et = blockIdx.x * blockDim.x + threadIdx.x;
    if (et >= ET_) return;
    int dst = (et < E_) ? edges[E_ + et] : (et - E_);
    atomicAdd(&deg[dst], 1);
}

__global__ __launch_bounds__(1024)
void csr_scan_k(const int* __restrict__ deg, int* __restrict__ row_ptr,
                int* __restrict__ cnt)
{
    __shared__ int s[1024];
    int t = threadIdx.x;
    int d = deg[t];
    s[t] = d;
    __syncthreads();
    for (int off = 1; off < 1024; off <<= 1) {
        int v = (t >= off) ? s[t - off] : 0;
        __syncthreads();
        s[t] += v;
        __syncthreads();
    }
    row_ptr[t] = s[t] - d;   // exclusive
    cnt[t] = s[t] - d;
    if (t == 1023) row_ptr[1024] = s[t];
}

__global__ void csr_fill_k(const int* __restrict__ edges, int* __restrict__ cnt,
                           int* __restrict__ col_src)
{
    int et = blockIdx.x * blockDim.x + threadIdx.x;
    if (et >= ET_) return;
    int src, dst;
    if (et < E_) { src = edges[et]; dst = edges[E_ + et]; }
    else         { src = et - E_;  dst = src; }
    int pos = atomicAdd(&cnt[dst], 1);
    col_src[pos] = src;
}

// ---------------------------------------------------------------------------
// Fused GAT softmax + aggregation + residual, in place on f32 feat (d_out).
// Vectorized: lane<50 handles 8 contiguous cols via uint4 wh loads; 4 j-slices
// (one per wave) reduced through padded LDS partials. Optionally emits bf16
// copy of feat (featb16) for the head gather.
// ---------------------------------------------------------------------------
__global__ __launch_bounds__(256)
void gat_k(const u16* __restrict__ wh,
           const float* __restrict__ a_s, const float* __restrict__ a_d,
           const int* __restrict__ row_ptr, const int* __restrict__ col_src,
           const float* __restrict__ gat_b, float* __restrict__ feat,
           u16* __restrict__ featb16)
{
    int gn = blockIdx.x;                  // b*1024 + n
    int b = gn >> 10, n = gn & 1023;
    int tid = threadIdx.x;
    __shared__ float s_ee[2][MAXD];
    __shared__ int   s_src[MAXD];
    __shared__ float s_misc[6];           // m0,m1,invz0,invz1,ad0,ad1
    __shared__ float s_part[4][50][9];    // +1 pad col: spread banks
    int start = row_ptr[n];
    int deg = row_ptr[n + 1] - start;

    if (tid < 64) {
        int lane = tid;
        float ad0 = a_d[(size_t)gn * 2 + 0];
        float ad1 = a_d[(size_t)gn * 2 + 1];
        float m0 = -1e30f, m1 = -1e30f;
        for (int j = lane; j < deg; j += 64) {
            int gs = (b << 10) + col_src[start + j];
            float e0 = a_s[(size_t)gs * 2 + 0] + ad0; e0 = (e0 > 0.f) ? e0 : 0.2f * e0;
            float e1 = a_s[(size_t)gs * 2 + 1] + ad1; e1 = (e1 > 0.f) ? e1 : 0.2f * e1;
            if (j < MAXD) { s_ee[0][j] = e0; s_ee[1][j] = e1; s_src[j] = gs; }
            m0 = fmaxf(m0, e0); m1 = fmaxf(m1, e1);
        }
        for (int off = 32; off; off >>= 1) {
            m0 = fmaxf(m0, __shfl_xor(m0, off));
            m1 = fmaxf(m1, __shfl_xor(m1, off));
        }
        float z0 = 0.f, z1 = 0.f;
        for (int j = lane; j < deg; j += 64) {
            float e0, e1;
            if (j < MAXD) { e0 = s_ee[0][j]; e1 = s_ee[1][j]; }
            else {
                int gs = (b << 10) + col_src[start + j];
                e0 = a_s[(size_t)gs * 2 + 0] + ad0; e0 = (e0 > 0.f) ? e0 : 0.2f * e0;
                e1 = a_s[(size_t)gs * 2 + 1] + ad1; e1 = (e1 > 0.f) ? e1 : 0.2f * e1;
            }
            float t0 = __expf(e0 - m0), t1 = __expf(e1 - m1);
            if (j < MAXD) { s_ee[0][j] = t0; s_ee[1][j] = t1; }
            z0 += t0; z1 += t1;
        }
        for (int off = 32; off; off >>= 1) {
            z0 += __shfl_xor(z0, off);
            z1 += __shfl_xor(z1, off);
        }
        if (lane == 0) {
            s_misc[0] = m0; s_misc[1] = m1;
            s_misc[2] = (z0 > 0.f) ? 1.f / z0 : 0.f;
            s_misc[3] = (z1 > 0.f) ? 1.f / z1 : 0.f;
            s_misc[4] = ad0; s_misc[5] = ad1;
        }
    }
    __syncthreads();

    int wv = tid >> 6, ln = tid & 63;
    if (ln < 50) {
        int h = (ln >= 25);
        float m = s_misc[h], ad = s_misc[4 + h];
        float acc[8] = {};
        for (int j = wv; j < deg; j += 4) {
            float w; int gs;
            if (j < MAXD) { w = s_ee[h][j]; gs = s_src[j]; }
            else {
                gs = (b << 10) + col_src[start + j];
                float e = a_s[(size_t)gs * 2 + h] + ad;
                e = (e > 0.f) ? e : 0.2f * e;
                w = __expf(e - m);
            }
            uint4 q = *(const uint4*)(wh + (size_t)gs * OUT_ + ln * 8);
            acc[0] += w * u2f((u16)(q.x & 0xffff));
            acc[1] += w * u2f((u16)(q.x >> 16));
            acc[2] += w * u2f((u16)(q.y & 0xffff));
            acc[3] += w * u2f((u16)(q.y >> 16));
            acc[4] += w * u2f((u16)(q.z & 0xffff));
            acc[5] += w * u2f((u16)(q.z >> 16));
            acc[6] += w * u2f((u16)(q.w & 0xffff));
            acc[7] += w * u2f((u16)(q.w >> 16));
        }
        #pragma unroll
        for (int k = 0; k < 8; ++k) s_part[wv][ln][k] = acc[k];
    }
    __syncthreads();
    if (tid < 50) {
        int h = (tid >= 25);
        float iz = s_misc[2 + h];
        size_t base = (size_t)gn * OUT_ + tid * 8;
        float4 f0 = *(const float4*)(feat + base);
        float4 f1 = *(const float4*)(feat + base + 4);
        float fv[8] = { f0.x, f0.y, f0.z, f0.w, f1.x, f1.y, f1.z, f1.w };
        float o[8];
        #pragma unroll
        for (int k = 0; k < 8; ++k) {
            float s = s_part[0][tid][k] + s_part[1][tid][k] +
                      s_part[2][tid][k] + s_part[3][tid][k];
            o[k] = fv[k] + s * iz + gat_b[tid * 8 + k];
        }
        *(float4*)(feat + base)     = make_float4(o[0], o[1], o[2], o[3]);
        *(float4*)(feat + base + 4) = make_float4(o[4], o[5], o[6], o[7]);
        if (featb16) {
            uint4 bq;
            bq.x = pack2(o[0], o[1]); bq.y = pack2(o[2], o[3]);
            bq.z = pack2(o[4], o[5]); bq.w = pack2(o[6], o[7]);
            *(uint4*)(featb16 + base) = bq;
        }
    }
}

// ---------------------------------------------------------------------------
// Final tiny GEMM: pred[e,:] = p2[e,:] @ w3[400,3] + b3.
// 4 waves/block, each wave does 4 edges; per-lane w3 slice held in registers.
// ---------------------------------------------------------------------------
__global__ __launch_bounds__(256)
void head3_k(const u16* __restrict__ p2, const float* __restrict__ w3,
             const float* __restrict__ b3, float* __restrict__ out,
             int row_base, int nrows)
{
    int wv = threadIdx.x >> 6, lane = threadIdx.x & 63;
    float w3r[24];
    if (lane < 50) {
        #pragma unroll
        for (int q = 0; q < 6; ++q) {
            float4 v = *(const float4*)(w3 + lane * 24 + q * 4);
            w3r[q * 4 + 0] = v.x; w3r[q * 4 + 1] = v.y;
            w3r[q * 4 + 2] = v.z; w3r[q * 4 + 3] = v.w;
        }
    }
    int e0 = blockIdx.x * 16 + wv * 4;
    for (int ei = 0; ei < 4; ++ei) {
        int e = e0 + ei;
        if (e >= nrows) break;
        float s0 = 0, s1 = 0, s2 = 0;
        if (lane < 50) {
            uint4 q = *(const uint4*)(p2 + (size_t)e * OUT_ + lane * 8);
            float f[8];
            f[0] = u2f((u16)(q.x & 0xffff)); f[1] = u2f((u16)(q.x >> 16));
            f[2] = u2f((u16)(q.y & 0xffff)); f[3] = u2f((u16)(q.y >> 16));
            f[4] = u2f((u16)(q.z & 0xffff)); f[5] = u2f((u16)(q.z >> 16));
            f[6] = u2f((u16)(q.w & 0xffff)); f[7] = u2f((u16)(q.w >> 16));
            #pragma unroll
            for (int k = 0; k < 8; ++k) {
                s0 += f[k] * w3r[k * 3 + 0];
                s1 += f[k] * w3r[k * 3 + 1];
                s2 += f[k] * w3r[k * 3 + 2];
            }
        }
        for (int off = 32; off; off >>= 1) {
            s0 += __shfl_xor(s0, off);
            s1 += __shfl_xor(s1, off);
            s2 += __shfl_xor(s2, off);
        }
        if (lane == 0) {
            size_t o = (size_t)FEAT_ELEMS + (size_t)(row_base + e) * 3;
            out[o + 0] = s0 + b3[0];
            out[o + 1] = s1 + b3[1];
            out[o + 2] = s2 + b3[2];
        }
    }
}

extern "C" void kernel_launch(void* const* d_in, const int* in_sizes, int n_in,
                              void* d_out, int out_size, void* d_ws, size_t ws_size,
                              hipStream_t stream)
{
    const float* patch  = (const float*)d_in[0];
    const int*   edges  = (const int*)d_in[1];
    const float* enc_w1 = (const float*)d_in[2];
    const float* enc_b1 = (const float*)d_in[3];
    const float* enc_w2 = (const float*)d_in[4];
    const float* enc_b2 = (const float*)d_in[5];
    const float* gat_w  = (const float*)d_in[6];
    const float* att_s  = (const float*)d_in[7];
    const float* att_d  = (const float*)d_in[8];
    const float* gat_b  = (const float*)d_in[9];
    const float* h_w1   = (const float*)d_in[10];
    const float* h_b1   = (const float*)d_in[11];
    const float* h_w2   = (const float*)d_in[12];
    const float* h_b2   = (const float*)d_in[13];
    const float* h_w3   = (const float*)d_in[14];
    const float* h_b3   = (const float*)d_in[15];
    float* out  = (float*)d_out;
    float* feat = out;                          // f32 [32768,400] in d_out
    char*  ws   = (char*)d_ws;

    const int* src0 = edges;
    const int* dst0 = edges + E_;

    // --- mode select from ws_size (deterministic; graph-capture safe) ------
    const size_t R0 = 33554432ull, TAIL = 4194304ull;
    const size_t PER_B = 39321600ull;           // p1 (26.2M) + p2 (13.1M)
    int CB = 0;
    if (ws_size > R0 + TAIL) {
        size_t avail = ws_size - R0 - TAIL;
        if (avail >= 26214400ull)               // whb must fit
            for (int c = 32; c >= 1; c >>= 1)
                if ((size_t)c * PER_B <= avail) { CB = c; break; }
    }
    const bool big = (CB >= 1);

    u16 *enc1, *whb, *p1, *p2, *featb16, *w1t, *w2t, *gwt, *hw1t, *hw2t;
    float *a_s, *a_d; int *deg, *row_ptr, *cnt, *col_src;
    if (big) {
        enc1    = (u16*)ws;
        featb16 = (u16*)ws;                     // overlays enc1 (dead)
        whb     = (u16*)(ws + R0);
        p1      = (u16*)(ws + R0);              // overlays whb (dead in head)
        p2      = (u16*)(ws + R0 + (size_t)CB * 26214400ull);
        size_t tb = (ws_size - TAIL) & ~(size_t)255;
        w1t  = (u16*)(ws + tb);
        w2t  = (u16*)(ws + tb + 786432);
        gwt  = (u16*)(ws + tb + 1196032);
        hw1t = (u16*)(ws + tb + 1516032);
        hw2t = (u16*)(ws + tb + 2796032);
        a_s  = (float*)(ws + tb + 3436032);
        a_d  = (float*)(ws + tb + 3698176);
        deg  = (int*)(ws + tb + 3960320);
    } else {
        enc1    = (u16*)ws;
        whb     = (u16*)ws;
        p1      = (u16*)ws;
        featb16 = nullptr;
        p2      = (u16*)(ws + 26214400);
        w1t  = (u16*)(ws + 33554432);
        w2t  = (u16*)(ws + 34340864);
        gwt  = (u16*)(ws + 34750464);
        hw1t = (u16*)(ws + 39321600);
        hw2t = (u16*)(ws + 40601600);
        a_s  = (float*)(ws + 41241600);
        a_d  = (float*)(ws + 41503744);
        deg  = (int*)(ws + 41765888);
    }
    row_ptr = deg + 1024;
    cnt     = row_ptr + 1032;
    col_src = cnt + 1024;
    u16* zbuf = (u16*)(col_src + 17408);        // 256 B zero scratch (16B aligned)

    hipMemsetAsync(zbuf, 0, 256, stream);

    // weight transposes (bf16), tiny
    wt_k<<<(HID * IN_DIM + 255) / 256, 256, 0, stream>>>(enc_w1, w1t, IN_DIM, HID);
    wt_k<<<(OUT_ * HID + 255) / 256, 256, 0, stream>>>(enc_w2, w2t, HID, OUT_);
    wt_k<<<(OUT_ * OUT_ + 255) / 256, 256, 0, stream>>>(gat_w, gwt, OUT_, OUT_);
    wt_k<<<(PAIR_ * PAIR_ + 255) / 256, 256, 0, stream>>>(h_w1, hw1t, PAIR_, PAIR_);
    wt_k<<<(OUT_ * PAIR_ + 255) / 256, 256, 0, stream>>>(h_w2, hw2t, PAIR_, OUT_);

    // CSR by dst (batch-independent)
    hipMemsetAsync(deg, 0, 1024 * sizeof(int), stream);
    csr_count_k<<<(ET_ + 255) / 256, 256, 0, stream>>>(edges, deg);
    csr_scan_k<<<1, 1024, 0, stream>>>(deg, row_ptr, cnt);
    csr_fill_k<<<(ET_ + 255) / 256, 256, 0, stream>>>(edges, cnt, col_src);

    // encoder: enc1 = gelu(patch @ w1 + b1);  feat(d_out,f32) = enc1 @ w2 + b2
    mfma_gemm_k<0, true, true, false><<<dim3(HID / 128, (B_ * N_) / 128), 256, 0, stream>>>(
        patch, nullptr, w1t, enc_b1, enc1, nullptr, B_ * N_, HID, IN_DIM,
        nullptr, nullptr, nullptr, nullptr, 0, zbuf);
    mfma_gemm_k<1, false, true, true><<<dim3((OUT_ + 127) / 128, (B_ * N_) / 128), 256, 0, stream>>>(
        nullptr, enc1, w2t, enc_b2, nullptr, feat, B_ * N_, OUT_, HID,
        nullptr, nullptr, nullptr, nullptr, 0, zbuf);

    // GAT linear: wh = enc(feat f32) @ gat_w
    mfma_gemm_k<0, false, false, false><<<dim3((OUT_ + 127) / 128, (B_ * N_) / 128), 256, 0, stream>>>(
        feat, nullptr, gwt, nullptr, whb, nullptr, B_ * N_, OUT_, OUT_,
        nullptr, nullptr, nullptr, nullptr, 0, zbuf);

    scores_k<<<(B_ * N_) / 4, 256, 0, stream>>>(whb, att_s, att_d, a_s, a_d);
    gat_k<<<B_ * N_, 256, 0, stream>>>(whb, a_s, a_d, row_ptr, col_src,
                                       gat_b, feat, featb16);

    // predict head
    if (big) {
        for (int b0 = 0; b0 < B_; b0 += CB) {
            int Mr = CB * E_;
            mfma_gemm_k<2, true, true, false><<<dim3((PAIR_ + 127) / 128, Mr / 128), 256, 0, stream>>>(
                nullptr, nullptr, hw1t, h_b1, p1, nullptr, Mr, PAIR_, PAIR_,
                nullptr, featb16, src0, dst0, b0, zbuf);
            mfma_gemm_k<1, true, true, false><<<dim3((OUT_ + 127) / 128, Mr / 128), 256, 0, stream>>>(
                nullptr, p1, hw2t, h_b2, p2, nullptr, Mr, OUT_, PAIR_,
                nullptr, nullptr, nullptr, nullptr, 0, zbuf);
            head3_k<<<(Mr + 15) / 16, 256, 0, stream>>>(p2, h_w3, h_b3, out,
                                                        b0 * E_, Mr);
        }
    } else {
        for (int b = 0; b < B_; ++b) {
            const float* featb = feat + (size_t)b * N_ * OUT_;
            mfma_gemm_k<3, true, true, false><<<dim3((PAIR_ + 127) / 128, E_ / 128), 256, 0, stream>>>(
                nullptr, nullptr, hw1t, h_b1, p1, nullptr, E_, PAIR_, PAIR_,
                featb, nullptr, src0, dst0, 0, zbuf);
            mfma_gemm_k<1, true, true, false><<<dim3((OUT_ + 127) / 128, E_ / 128), 256, 0, stream>>>(
                nullptr, p1, hw2t, h_b2, p2, nullptr, E_, OUT_, PAIR_,
                nullptr, nullptr, nullptr, nullptr, 0, zbuf);
            head3_k<<<(E_ + 15) / 16, 256, 0, stream>>>(p2, h_w3, h_b3, out,
                                                        b * E_, E_);
        }
    }
}